// Round 9
// baseline (128.641 us; speedup 1.0000x reference)
//
#include <hip/hip_runtime.h>
#include <math.h>

#define NCLS 676
#define NEG_SENTINEL -3.0e38f  // finite stand-in for -inf (checker: inf-inf=nan)
#define LN2F 0.6931471805599453f
#define JPAD 768     // padded j-axis of weight tables
#define ROWS 768     // aD/bD diag-row stride: 256 data cols + guards
#define QIP_OFF 692  // qip base (16-float front guard after pw)
#define WSE_OFF 1460
#define EXPS_OFF 20660            // 4096 ints: 64 blocks x 64 lanes
#define RING_OFF 24756            // 16 slots x 256 floats (16B aligned)
#define CTL_OFF 28852             // [0]=producer progress, [1]=flusher progress
#define SHM_TOT 28864             // floats = 115 KB LDS

struct f4u { float x, y, z, w; };  // align-4 quad for unaligned global stores

__device__ __forceinline__ float dpp_shr1(float x) {  // lane n <- n-1, lane0 0
  return __int_as_float(
      __builtin_amdgcn_update_dpp(0, __float_as_int(x), 0x138, 0xF, 0xF, false));
}
__device__ __forceinline__ float dpp_shl1(float x) {  // lane n <- n+1, lane63 0
  return __int_as_float(
      __builtin_amdgcn_update_dpp(0, __float_as_int(x), 0x130, 0xF, 0xF, false));
}
__device__ __forceinline__ int dpp_shr1_i(int x) {
  return __builtin_amdgcn_update_dpp(0, x, 0x138, 0xF, 0xF, false);
}
__device__ __forceinline__ int dpp_shl1_i(int x) {
  return __builtin_amdgcn_update_dpp(0, x, 0x130, 0xF, 0xF, false);
}
__device__ __forceinline__ float pow2c(int d) {  // exact 2^d, clamped
  d = min(max(d, -126), 126);
  return __int_as_float((d + 127) << 23);
}

// Row-owned anti-diagonal DP (prob-domain BFP, R8 math unchanged) with a
// producer/consumer split: wave 0 runs the DP and writes each diagonal to an
// LDS ring (ds_write_b128, compile-time slot offsets, no vmcnt on the
// critical wave); wave 1 spins on the ring and copies diagonals to global
// (absorbing all global-store latency), then dumps the exponent table.
// block 0: alpha (d=1..510), block 1: beta (s=509..0).
__global__ __launch_bounds__(128) void k_diag(const int* __restrict__ ar,
                                              const int* __restrict__ en,
                                              const float* __restrict__ wts,
                                              float* __restrict__ aD,
                                              float* __restrict__ bD,
                                              int* __restrict__ aEbG,
                                              int* __restrict__ bEbG,
                                              int* __restrict__ redcnt) {
  const int tid = threadIdx.x;
  const int lane = tid & 63;
  const int wid = tid >> 6;
  const bool alpha = (blockIdx.x == 0);
  __shared__ alignas(16) float shm[SHM_TOT];
  int* shmI = (int*)shm;
  float* pw = shm;             // exp(weights), 676
  float* qip = shm + QIP_OFF;  // exp(w_ins) by jpad, zero-padded
  float* wsE = shm + WSE_OFF;  // 25 x JPAD: exp(w_sub[a]) by jpad, padded

  for (int c = tid; c < NCLS; c += 128) pw[c] = __expf(wts[c]);
  {  // zero everything after pw (guards, tables, exps, ring, ctl)
    float4* z = (float4*)(shm + NCLS);
    const int nz = (SHM_TOT - NCLS) / 4;
    for (int t = tid; t < nz; t += 128) z[t] = make_float4(0.f, 0.f, 0.f, 0.f);
  }
  __syncthreads();
  for (int j = tid; j < 256; j += 128) {
    int e = en[j];
    qip[255 + j] = pw[26 + e];
#pragma unroll
    for (int a = 0; a < 25; ++a) wsE[a * JPAD + 255 + j] = pw[51 + 25 * a + e];
  }
  if (tid == 0) {
    if (alpha) { shmI[CTL_OFF] = 0; shmI[CTL_OFF + 1] = 0; }
    else       { shmI[CTL_OFF] = 600; shmI[CTL_OFF + 1] = 518; }
  }
  if (tid == 1) {
    if (alpha) aD[0 * ROWS + 256 + 0] = 1.0f;        // alpha diag-0 init cell
    else       bD[510 * ROWS + 256 + 255] = 1.0f;    // beta diag-510 init cell
  }
  if (tid == 2) *redcnt = 0;  // for k_red's last-block epilogue
  __syncthreads();

  volatile int* prodv = (volatile int*)&shmI[CTL_OFF];
  volatile int* flcv = (volatile int*)&shmI[CTL_OFF + 1];

  if (wid == 0) {
    // ---------------- DP wave ----------------
    const int i0 = 4 * lane;
    const int rcol = 252 - i0;  // ring col base (16B aligned), see mapping note
    float wdl[4];
    const float* rowp[4];
#pragma unroll
    for (int k = 0; k < 4; ++k) {
      int a = ar[i0 + k];
      wdl[k] = pw[1 + a];
      rowp[k] = wsE + a * JPAD;
    }
    float P1[4] = {0.f, 0.f, 0.f, 0.f};
    float P2[4] = {0.f, 0.f, 0.f, 0.f};
    int e1 = 0;
    int* epl = &shmI[EXPS_OFF] + lane;

    if (alpha) {
      // A[i][j] = pd_i*A[i-1][j] + ps_ij*A[i-1][j-1] + pi_j*A[i][j-1]
      if (lane == 0) P1[0] = 1.f;
      int e0 = 252 - i0;
      int d0w = 1;
      float W0[4][12], Q0[12], W1[4][12], Q1[12];

#define LOAD_A(EB, W, Q)                                                   \
  {                                                                        \
    _Pragma("unroll") for (int k = 0; k < 4; ++k) {                        \
      const float4* p = (const float4*)(rowp[k] + (EB));                   \
      float4 va = p[0], vb = p[1], vc = p[2];                              \
      W[k][0] = va.x; W[k][1] = va.y; W[k][2] = va.z; W[k][3] = va.w;      \
      W[k][4] = vb.x; W[k][5] = vb.y; W[k][6] = vb.z; W[k][7] = vb.w;      \
      W[k][8] = vc.x; W[k][9] = vc.y; W[k][10] = vc.z; W[k][11] = vc.w;    \
    }                                                                      \
    const float4* q = (const float4*)(qip + (EB));                         \
    float4 qa = q[0], qb = q[1], qc = q[2];                                \
    Q[0] = qa.x; Q[1] = qa.y; Q[2] = qa.z; Q[3] = qa.w;                    \
    Q[4] = qb.x; Q[5] = qb.y; Q[6] = qb.z; Q[7] = qb.w;                    \
    Q[8] = qc.x; Q[9] = qc.y; Q[10] = qc.z; Q[11] = qc.w;                  \
  }

#define PROC_A(W, Q, PH)                                                   \
  {                                                                        \
    while (*flcv < d0w - 9) __builtin_amdgcn_s_sleep(2);                   \
    __threadfence_block();                                                 \
    epl[0] = e1; epl += 64;                                                \
    int t1e = dpp_shr1_i(e1);                                              \
    float f1n = pow2c(t1e - e1);                                           \
    _Pragma("unroll") for (int u = 0; u < 8; ++u) {                        \
      float pm1 = dpp_shr1(P1[3]) * f1n;                                   \
      float pm2 = dpp_shr1(P2[3]) * f1n;                                   \
      float cu[4];                                                         \
      _Pragma("unroll") for (int k = 0; k < 4; ++k) {                      \
        float a1 = (k == 0) ? pm1 : P1[k - 1];                             \
        float a2 = (k == 0) ? pm2 : P2[k - 1];                             \
        cu[k] = fmaf(wdl[k], a1,                                           \
                     fmaf(W[k][4 + u - k], a2, Q[4 + u - k] * P1[k]));     \
      }                                                                    \
      *(float4*)&shm[RING_OFF + ((((PH) + u) & 15) << 8) + rcol] =         \
          make_float4(cu[3], cu[2], cu[1], cu[0]);                         \
      _Pragma("unroll") for (int k = 0; k < 4; ++k) {                      \
        P2[k] = P1[k]; P1[k] = cu[k];                                      \
      }                                                                    \
    }                                                                      \
    __threadfence_block();                                                 \
    if (lane == 0) *prodv = d0w + 7;                                       \
    float m = fmaxf(fmaxf(P1[0], P1[1]), fmaxf(P1[2], P1[3]));             \
    int ex = (m > 0.f) ? ((__float_as_int(m) >> 23) - 126) : (t1e - e1);   \
    float sc = pow2c(-ex);                                                 \
    _Pragma("unroll") for (int k = 0; k < 4; ++k) {                        \
      P1[k] *= sc; P2[k] *= sc;                                            \
    }                                                                      \
    e1 += ex;                                                              \
    d0w += 8;                                                              \
  }

      LOAD_A(e0, W0, Q0);
      for (int it = 0; it < 31; ++it) {
        LOAD_A(e0 + 8, W1, Q1);
        PROC_A(W0, Q0, 1);
        LOAD_A(e0 + 16, W0, Q0);
        PROC_A(W1, Q1, 9);
        e0 += 16;
      }
      LOAD_A(e0 + 8, W1, Q1);
      PROC_A(W0, Q0, 1);  // d 497..504
      PROC_A(W1, Q1, 9);  // d 505..512 (511/512 stay in ring, never flushed)
    } else {
      // B[i][j] = pd_i*B[i+1][j] + ps_ij*B[i+1][j+1] + pi_{j+1}*B[i][j+1]
      if (lane == 63) P1[3] = 1.f;  // B[255][255] (diag 510, init cell)
      float qi0 = pw[26 + en[i0]];  // reuse table: winc built like R8
      (void)qi0;
      int e0 = 764 - i0;
      int s0w = 509;
      float W0[4][16], Q0[16], W1[4][16], Q1[16];

#define LOAD_B(EB, W, Q)                                                   \
  {                                                                        \
    _Pragma("unroll") for (int k = 0; k < 4; ++k) {                        \
      const float4* p = (const float4*)(rowp[k] + (EB));                   \
      float4 va = p[0], vb = p[1], vc = p[2], vd = p[3];                   \
      W[k][0] = va.x; W[k][1] = va.y; W[k][2] = va.z; W[k][3] = va.w;      \
      W[k][4] = vb.x; W[k][5] = vb.y; W[k][6] = vb.z; W[k][7] = vb.w;      \
      W[k][8] = vc.x; W[k][9] = vc.y; W[k][10] = vc.z; W[k][11] = vc.w;    \
      W[k][12] = vd.x; W[k][13] = vd.y; W[k][14] = vd.z; W[k][15] = vd.w;  \
    }                                                                      \
    const float4* q = (const float4*)(qip + (EB));                         \
    float4 qa = q[0], qb = q[1], qc = q[2], qd = q[3];                     \
    Q[0] = qa.x; Q[1] = qa.y; Q[2] = qa.z; Q[3] = qa.w;                    \
    Q[4] = qb.x; Q[5] = qb.y; Q[6] = qb.z; Q[7] = qb.w;                    \
    Q[8] = qc.x; Q[9] = qc.y; Q[10] = qc.z; Q[11] = qc.w;                  \
    Q[12] = qd.x; Q[13] = qd.y; Q[14] = qd.z; Q[15] = qd.w;                \
  }

#define PROC_B(W, Q, PH)                                                   \
  {                                                                        \
    while (*flcv > s0w + 9) __builtin_amdgcn_s_sleep(2);                   \
    __threadfence_block();                                                 \
    epl[0] = e1; epl += 64;                                                \
    int t1e = dpp_shl1_i(e1);                                              \
    float f1n = pow2c(t1e - e1);                                           \
    _Pragma("unroll") for (int u = 0; u < 8; ++u) {                        \
      float pm1 = dpp_shl1(P1[0]) * f1n;                                   \
      float pm2 = dpp_shl1(P2[0]) * f1n;                                   \
      float cu[4];                                                         \
      _Pragma("unroll") for (int k = 0; k < 4; ++k) {                      \
        float a1 = (k == 3) ? pm1 : P1[k + 1];                             \
        float a2 = (k == 3) ? pm2 : P2[k + 1];                             \
        cu[k] = fmaf(wdl[k], a1,                                           \
                     fmaf(W[k][12 - u - k], a2, Q[13 - u - k] * P1[k]));   \
      }                                                                    \
      *(float4*)&shm[RING_OFF + ((((PH) - u) & 15) << 8) + rcol] =         \
          make_float4(cu[3], cu[2], cu[1], cu[0]);                         \
      _Pragma("unroll") for (int k = 0; k < 4; ++k) {                      \
        P2[k] = P1[k]; P1[k] = cu[k];                                      \
      }                                                                    \
    }                                                                      \
    __threadfence_block();                                                 \
    if (lane == 0) *prodv = s0w - 7;                                       \
    float m = fmaxf(fmaxf(P1[0], P1[1]), fmaxf(P1[2], P1[3]));             \
    int ex = (m > 0.f) ? ((__float_as_int(m) >> 23) - 126) : (t1e - e1);   \
    float sc = pow2c(-ex);                                                 \
    _Pragma("unroll") for (int k = 0; k < 4; ++k) {                        \
      P1[k] *= sc; P2[k] *= sc;                                            \
    }                                                                      \
    e1 += ex;                                                              \
    s0w -= 8;                                                              \
  }

      LOAD_B(e0, W0, Q0);
      for (int it = 0; it < 31; ++it) {
        LOAD_B(e0 - 8, W1, Q1);
        PROC_B(W0, Q0, 13);
        LOAD_B(e0 - 16, W0, Q0);
        PROC_B(W1, Q1, 5);
        e0 -= 16;
      }
      LOAD_B(e0 - 8, W1, Q1);
      PROC_B(W0, Q0, 13);  // s 13..6
      PROC_B(W1, Q1, 5);   // s 5..-2 (-1/-2 stay in ring, never flushed)
    }
  } else {
    // ---------------- flusher wave ----------------
    // ring col r' -> global col r' + d + 1 (alpha) / r' + s + 1 (beta)
    if (alpha) {
      float* gp = aD + 1 * ROWS + 2 + 4 * lane;  // d=1: d*768 + d+1 + 4F
      for (int g = 1; g <= 505; g += 8) {
        const int tgt = g + 7;
        while (*prodv < tgt) __builtin_amdgcn_s_sleep(2);
        __threadfence_block();
        for (int u = 0; u < 8; ++u) {
          int d = g + u;
          if (d <= 510) {
            float4 v = *(const float4*)&shm[RING_OFF + ((d & 15) << 8) +
                                            (lane << 2)];
            *(f4u*)gp = f4u{v.x, v.y, v.z, v.w};
          }
          gp += ROWS + 1;
        }
        if (lane == 0) *flcv = g + 7;
      }
      const int4* es = (const int4*)&shm[EXPS_OFF];
      int4* ed = (int4*)aEbG;
      for (int t = lane; t < 1024; t += 64) ed[t] = es[t];
    } else {
      float* gp = bD + 509 * ROWS + 510 + 4 * lane;  // s=509: s*768 + s+1 + 4F
      for (int g = 509; g >= 5; g -= 8) {
        const int tgt = g - 7;
        while (*prodv > tgt) __builtin_amdgcn_s_sleep(2);
        __threadfence_block();
        for (int u = 0; u < 8; ++u) {
          int s = g - u;
          if (s >= 0) {
            float4 v = *(const float4*)&shm[RING_OFF + ((s & 15) << 8) +
                                            (lane << 2)];
            *(f4u*)gp = f4u{v.x, v.y, v.z, v.w};
          }
          gp -= ROWS + 1;
        }
        if (lane == 0) *flcv = g - 7;
      }
      const int4* es = (const int4*)&shm[EXPS_OFF];
      int4* ed = (int4*)bEbG;
      for (int t = lane; t < 1024; t += 64) ed[t] = es[t];
    }
  }
}

// 64 blocks x 1024 threads, 8 diags/block; log-form terms (NaN/overflow
// impossible). Last block (atomic ticket) sums Spart and writes the output —
// no dispatch-order assumption: only the block whose add returns 63 does it.
__global__ __launch_bounds__(1024) void k_red(const int* __restrict__ ar,
                                              const int* __restrict__ en,
                                              const float* __restrict__ aD,
                                              const float* __restrict__ bD,
                                              const int* __restrict__ aEb,
                                              const int* __restrict__ bEb,
                                              float* __restrict__ Spart,
                                              const float* __restrict__ wts,
                                              float* __restrict__ out,
                                              int* __restrict__ redcnt) {
  const int tid = threadIdx.x;
  const int j = tid & 255;
  __shared__ float bins[NCLS];
  __shared__ int lastf;
  for (int c = tid; c < NCLS; c += 1024) bins[c] = 0.f;
  __syncthreads();
  const float M = __logf(aD[510 * ROWS + 256 + 255]) +
                  (float)aEb[63 * 64 + 63] * LN2F + 16.0f;
  const int e = en[j];
#pragma unroll
  for (int rr = 0; rr < 2; ++rr) {
    const int d = blockIdx.x * 8 + (tid >> 8) + rr * 4;
    if (d <= 510) {
      const int i = d - j;
      if (i >= 0 && i <= 255) {
        const float bM = bD[d * ROWS + 256 + j];
        if (bM > 0.f) {
          const int bEx = (d == 510) ? 0 : bEb[((509 - d) >> 3) * 64 + (i >> 2)];
          const float lb = __logf(bM) + (float)bEx * LN2F - M;
          const int a = ar[i];
          if (i >= 1) {
            float aM = aD[(d - 1) * ROWS + 256 + j];
            if (aM > 0.f) {
              int eA = (d == 1) ? 0 : aEb[((d - 2) >> 3) * 64 + ((i - 1) >> 2)];
              float L = __logf(aM) + (float)eA * LN2F + lb;
              atomicAdd(&bins[1 + a], __expf(fminf(L, 0.f)));
            }
          }
          if (j >= 1) {
            float aM = aD[(d - 1) * ROWS + 256 + j - 1];
            if (aM > 0.f) {
              int eA = (d == 1) ? 0 : aEb[((d - 2) >> 3) * 64 + (i >> 2)];
              float L = __logf(aM) + (float)eA * LN2F + lb;
              atomicAdd(&bins[26 + e], __expf(fminf(L, 0.f)));
            }
            if (i >= 1) {
              float aM2 = aD[(d - 2) * ROWS + 256 + j - 1];
              if (aM2 > 0.f) {
                int eA2 =
                    (d == 2) ? 0 : aEb[((d - 3) >> 3) * 64 + ((i - 1) >> 2)];
                float L2 = __logf(aM2) + (float)eA2 * LN2F + lb;
                atomicAdd(&bins[51 + 25 * a + e], __expf(fminf(L2, 0.f)));
              }
            }
          }
        }
      }
    }
  }
  __syncthreads();
  for (int c = tid; c < NCLS; c += 1024) Spart[blockIdx.x * NCLS + c] = bins[c];
  __threadfence();
  if (tid == 0) lastf = (atomicAdd(redcnt, 1) == 63) ? 1 : 0;
  __syncthreads();
  if (lastf == 0) return;
  __threadfence();  // acquire: other blocks' Spart now visible
  if (tid < NCLS) {
    float s = 0.f;
    for (int b = 0; b < 64; ++b) s += Spart[b * NCLS + tid];
    out[tid] = (tid != 0 && s > 0.f) ? (wts[tid] + M + __logf(s)) : NEG_SENTINEL;
  }
}

extern "C" void kernel_launch(void* const* d_in, const int* in_sizes, int n_in,
                              void* d_out, int out_size, void* d_ws, size_t ws_size,
                              hipStream_t stream) {
  const int* ar = (const int*)d_in[0];
  const int* en = (const int*)d_in[1];
  const float* wts = (const float*)d_in[2];
  float* aD = (float*)d_ws;                  // 514 diag-rows x 768
  float* bDraw = aD + 514 * ROWS;            // 514 diag-rows x 768
  float* bD = bDraw + 2 * ROWS;
  int* aEb = (int*)(bDraw + 514 * ROWS);     // 64 blocks x 64 lanes
  int* bEb = aEb + 4096;
  float* Spart = (float*)(bEb + 4096);       // 64 x 676 partial class sums
  int* redcnt = (int*)(Spart + 64 * NCLS);   // last-block ticket
  k_diag<<<2, 128, 0, stream>>>(ar, en, wts, aD, bD, aEb, bEb, redcnt);
  k_red<<<64, 1024, 0, stream>>>(ar, en, aD, bD, aEb, bEb, Spart, wts,
                                 (float*)d_out, redcnt);
}

// Round 10
// 97.631 us; speedup vs baseline: 1.3176x; 1.3176x over previous
//
#include <hip/hip_runtime.h>
#include <math.h>

#define NCLS 676
#define NEG_SENTINEL -3.0e38f  // finite stand-in for -inf (checker: inf-inf=nan)
#define LN2F 0.6931471805599453f
#define JPAD 768     // padded j-axis of weight tables
#define ROWS 768     // aD/bD diag-row stride: 256 data cols + guards
#define QIP_OFF 692  // qip base (16-float front guard after pw)
#define WSE_OFF 1460
#define SHM_FLOATS (WSE_OFF + 25 * JPAD)  // 20660 floats = 82.6 KB
#define MAGIC 0x13579BDFu

struct f4u { float x, y, z, w; };  // align-4 quad for unaligned global stores

__device__ __forceinline__ float dpp_shr1(float x) {  // lane n <- n-1, lane0 0
  return __int_as_float(
      __builtin_amdgcn_update_dpp(0, __float_as_int(x), 0x138, 0xF, 0xF, false));
}
__device__ __forceinline__ float dpp_shl1(float x) {  // lane n <- n+1, lane63 0
  return __int_as_float(
      __builtin_amdgcn_update_dpp(0, __float_as_int(x), 0x130, 0xF, 0xF, false));
}
__device__ __forceinline__ int dpp_shr1_i(int x) {
  return __builtin_amdgcn_update_dpp(0, x, 0x138, 0xF, 0xF, false);
}
__device__ __forceinline__ int dpp_shl1_i(int x) {
  return __builtin_amdgcn_update_dpp(0, x, 0x130, 0xF, 0xF, false);
}
__device__ __forceinline__ float pow2c(int d) {  // exact 2^d, clamped
  d = min(max(d, -126), 126);
  return __int_as_float((d + 127) << 23);
}

// Fused kernel. Blocks 0,1: R8's row-owned anti-diagonal BFP DP (wave 0 only;
// 83 KB LDS -> 1 block/CU so DP CUs are private). Blocks 2..129: keep their
// CUs busy (clock-governor probe) until both DP flags are set, then each
// reduces 4 diagonals into LDS bins and atomically flushes to global S.
// Cross-XCD correctness: DP blocks __threadfence (L2 writeback) before a
// device-scope release flag store; workers spin relaxed, then one acquire
// load (L1/L2 invalidate) before reading aD/bD/aEb/bEb.
__global__ __launch_bounds__(256) void k_fused(const int* __restrict__ ar,
                                               const int* __restrict__ en,
                                               const float* __restrict__ wts,
                                               float* __restrict__ aD,
                                               float* __restrict__ bD,
                                               int* __restrict__ aEb,
                                               int* __restrict__ bEb,
                                               float* __restrict__ S,
                                               unsigned* __restrict__ flags) {
  const int tid = threadIdx.x;
  __shared__ alignas(16) float shm[SHM_FLOATS];

  if (blockIdx.x >= 2) {
    // ---------------- worker block: spin, then k_red slice ----------------
    float* bins = shm;  // 676 floats
    int* ctl = (int*)(shm + 680);
    for (int c = tid; c < NCLS; c += 256) bins[c] = 0.f;
    if (tid == 0) ctl[0] = 0;
    __syncthreads();
    if (tid == 0) {
      while (__hip_atomic_load(&flags[0], __ATOMIC_RELAXED,
                               __HIP_MEMORY_SCOPE_AGENT) != MAGIC ||
             __hip_atomic_load(&flags[1], __ATOMIC_RELAXED,
                               __HIP_MEMORY_SCOPE_AGENT) != MAGIC)
        __builtin_amdgcn_s_sleep(16);
      (void)__hip_atomic_load(&flags[0], __ATOMIC_ACQUIRE,
                              __HIP_MEMORY_SCOPE_AGENT);  // inv L1/L2
      __hip_atomic_store(&ctl[0], 1, __ATOMIC_RELEASE,
                         __HIP_MEMORY_SCOPE_WORKGROUP);
    } else if (tid >= 64) {
      // waves 1-3: dependent-FMA burn to keep the DPM clock up during the DP
      float x = 1.0f + (float)tid;
      while (__hip_atomic_load(&ctl[0], __ATOMIC_RELAXED,
                               __HIP_MEMORY_SCOPE_WORKGROUP) == 0) {
#pragma unroll
        for (int z = 0; z < 128; ++z) x = fmaf(x, 1.0000001f, 1.0e-7f);
      }
      if (x == 123.456f) atomicAdd(&S[0], 0.f);  // keep x live; never taken
    }
    __syncthreads();
    const float M = __logf(aD[510 * ROWS + 256 + 255]) +
                    (float)aEb[63 * 64 + 63] * LN2F + 16.0f;
    const int j = tid;
    const int e = en[j];
#pragma unroll
    for (int u = 0; u < 4; ++u) {
      const int d = ((int)blockIdx.x - 2) * 4 + u;
      if (d <= 510) {
        const int i = d - j;
        if (i >= 0 && i <= 255) {
          const float bM = bD[d * ROWS + 256 + j];
          if (bM > 0.f) {
            const int bEx =
                (d == 510) ? 0 : bEb[((509 - d) >> 3) * 64 + (i >> 2)];
            const float lb = __logf(bM) + (float)bEx * LN2F - M;
            const int a = ar[i];
            if (i >= 1) {
              float aM = aD[(d - 1) * ROWS + 256 + j];
              if (aM > 0.f) {
                int eA =
                    (d == 1) ? 0 : aEb[((d - 2) >> 3) * 64 + ((i - 1) >> 2)];
                float L = __logf(aM) + (float)eA * LN2F + lb;
                atomicAdd(&bins[1 + a], __expf(fminf(L, 0.f)));
              }
            }
            if (j >= 1) {
              float aM = aD[(d - 1) * ROWS + 256 + j - 1];
              if (aM > 0.f) {
                int eA = (d == 1) ? 0 : aEb[((d - 2) >> 3) * 64 + (i >> 2)];
                float L = __logf(aM) + (float)eA * LN2F + lb;
                atomicAdd(&bins[26 + e], __expf(fminf(L, 0.f)));
              }
              if (i >= 1) {
                float aM2 = aD[(d - 2) * ROWS + 256 + j - 1];
                if (aM2 > 0.f) {
                  int eA2 =
                      (d == 2) ? 0 : aEb[((d - 3) >> 3) * 64 + ((i - 1) >> 2)];
                  float L2 = __logf(aM2) + (float)eA2 * LN2F + lb;
                  atomicAdd(&bins[51 + 25 * a + e], __expf(fminf(L2, 0.f)));
                }
              }
            }
          }
        }
      }
    }
    __syncthreads();
    for (int c = tid; c < NCLS; c += 256)
      if (bins[c] != 0.f) atomicAdd(&S[c], bins[c]);
    return;
  }

  // ---------------- DP blocks 0 (alpha) / 1 (beta): R8 verbatim ----------
  float* pw = shm;             // exp(weights), 676
  float* qip = shm + QIP_OFF;  // exp(w_ins) by jpad, zero-padded
  float* wsE = shm + WSE_OFF;  // 25 x JPAD: exp(w_sub[a]) by jpad, padded
  for (int c = tid; c < NCLS; c += 256) pw[c] = __expf(wts[c]);
  {  // zero guards + tables after pw (16B aligned at 676*4)
    float4* z = (float4*)(shm + NCLS);
    const int nz = (SHM_FLOATS - NCLS) / 4;
    for (int t = tid; t < nz; t += 256) z[t] = make_float4(0.f, 0.f, 0.f, 0.f);
  }
  if (blockIdx.x == 0)
    for (int c = tid; c < NCLS; c += 256) S[c] = 0.f;  // flushed before flag
  __syncthreads();
  {
    int j = tid;  // 256 threads: one column each
    int ee = en[j];
    qip[255 + j] = pw[26 + ee];
#pragma unroll
    for (int a = 0; a < 25; ++a) wsE[a * JPAD + 255 + j] = pw[51 + 25 * a + ee];
  }
  __syncthreads();
  if (tid >= 64) return;  // waves 1-3 done (no further barriers below)
  const int lane = tid;

  const int i0 = 4 * lane;
  float wdl[4];
  const float* rowp[4];
#pragma unroll
  for (int k = 0; k < 4; ++k) {
    int a = ar[i0 + k];
    wdl[k] = pw[1 + a];
    rowp[k] = wsE + a * JPAD;
  }
  float P1[4] = {0.f, 0.f, 0.f, 0.f};
  float P2[4] = {0.f, 0.f, 0.f, 0.f};
  int e1 = 0;

  if (blockIdx.x == 0) {
    // A[i][j] = pd_i*A[i-1][j] + ps_ij*A[i-1][j-1] + pi_j*A[i][j-1]
    if (lane == 0) { P1[0] = 1.f; aD[0 * ROWS + 256] = 1.f; }
    int e0 = 252 - i0;
    float* sp = aD + ROWS + 256 + (1 - i0 - 3);
    int* ep = aEb + lane;
    float W0[4][12], Q0[12], W1[4][12], Q1[12];

#define LOAD_A(EB, W, Q)                                                   \
  {                                                                        \
    _Pragma("unroll") for (int k = 0; k < 4; ++k) {                        \
      const float4* p = (const float4*)(rowp[k] + (EB));                   \
      float4 va = p[0], vb = p[1], vc = p[2];                              \
      W[k][0] = va.x; W[k][1] = va.y; W[k][2] = va.z; W[k][3] = va.w;      \
      W[k][4] = vb.x; W[k][5] = vb.y; W[k][6] = vb.z; W[k][7] = vb.w;      \
      W[k][8] = vc.x; W[k][9] = vc.y; W[k][10] = vc.z; W[k][11] = vc.w;    \
    }                                                                      \
    const float4* q = (const float4*)(qip + (EB));                         \
    float4 qa = q[0], qb = q[1], qc = q[2];                                \
    Q[0] = qa.x; Q[1] = qa.y; Q[2] = qa.z; Q[3] = qa.w;                    \
    Q[4] = qb.x; Q[5] = qb.y; Q[6] = qb.z; Q[7] = qb.w;                    \
    Q[8] = qc.x; Q[9] = qc.y; Q[10] = qc.z; Q[11] = qc.w;                  \
  }

#define PROC_A(W, Q)                                                       \
  {                                                                        \
    *ep = e1; ep += 64;                                                    \
    int t1e = dpp_shr1_i(e1);                                              \
    float f1n = pow2c(t1e - e1);                                           \
    _Pragma("unroll") for (int u = 0; u < 8; ++u) {                        \
      float pm1 = dpp_shr1(P1[3]) * f1n;                                   \
      float pm2 = dpp_shr1(P2[3]) * f1n;                                   \
      float cu[4];                                                         \
      _Pragma("unroll") for (int k = 0; k < 4; ++k) {                      \
        float a1 = (k == 0) ? pm1 : P1[k - 1];                             \
        float a2 = (k == 0) ? pm2 : P2[k - 1];                             \
        cu[k] = fmaf(wdl[k], a1,                                           \
                     fmaf(W[k][4 + u - k], a2, Q[4 + u - k] * P1[k]));     \
      }                                                                    \
      *(f4u*)sp = f4u{cu[3], cu[2], cu[1], cu[0]};                         \
      sp += ROWS + 1;                                                      \
      _Pragma("unroll") for (int k = 0; k < 4; ++k) {                      \
        P2[k] = P1[k]; P1[k] = cu[k];                                      \
      }                                                                    \
    }                                                                      \
    float m = fmaxf(fmaxf(P1[0], P1[1]), fmaxf(P1[2], P1[3]));             \
    int ex = (m > 0.f) ? ((__float_as_int(m) >> 23) - 126) : (t1e - e1);   \
    float sc = pow2c(-ex);                                                 \
    _Pragma("unroll") for (int k = 0; k < 4; ++k) {                        \
      P1[k] *= sc; P2[k] *= sc;                                            \
    }                                                                      \
    e1 += ex;                                                              \
  }

    LOAD_A(e0, W0, Q0);
    for (int it = 0; it < 31; ++it) {
      LOAD_A(e0 + 8, W1, Q1);
      PROC_A(W0, Q0);
      LOAD_A(e0 + 16, W0, Q0);
      PROC_A(W1, Q1);
      e0 += 16;
    }
    LOAD_A(e0 + 8, W1, Q1);
    PROC_A(W0, Q0);  // d 497..504
    PROC_A(W1, Q1);  // d 505..512 (511/512 land in row pad)
  } else {
    // B[i][j] = pd_i*B[i+1][j] + ps_ij*B[i+1][j+1] + pi_{j+1}*B[i][j+1]
    if (lane == 63) P1[3] = 1.f;  // B[255][255] (diag 510)
    if (lane == 0) bD[510 * ROWS + 256 + 255] = 1.f;
    int e0 = 764 - i0;
    float* sp = bD + 509 * ROWS + 256 + (509 - i0 - 3);
    int* ep = bEb + lane;
    float W0[4][16], Q0[16], W1[4][16], Q1[16];

#define LOAD_B(EB, W, Q)                                                   \
  {                                                                        \
    _Pragma("unroll") for (int k = 0; k < 4; ++k) {                        \
      const float4* p = (const float4*)(rowp[k] + (EB));                   \
      float4 va = p[0], vb = p[1], vc = p[2], vd = p[3];                   \
      W[k][0] = va.x; W[k][1] = va.y; W[k][2] = va.z; W[k][3] = va.w;      \
      W[k][4] = vb.x; W[k][5] = vb.y; W[k][6] = vb.z; W[k][7] = vb.w;      \
      W[k][8] = vc.x; W[k][9] = vc.y; W[k][10] = vc.z; W[k][11] = vc.w;    \
      W[k][12] = vd.x; W[k][13] = vd.y; W[k][14] = vd.z; W[k][15] = vd.w;  \
    }                                                                      \
    const float4* q = (const float4*)(qip + (EB));                         \
    float4 qa = q[0], qb = q[1], qc = q[2], qd = q[3];                     \
    Q[0] = qa.x; Q[1] = qa.y; Q[2] = qa.z; Q[3] = qa.w;                    \
    Q[4] = qb.x; Q[5] = qb.y; Q[6] = qb.z; Q[7] = qb.w;                    \
    Q[8] = qc.x; Q[9] = qc.y; Q[10] = qc.z; Q[11] = qc.w;                  \
    Q[12] = qd.x; Q[13] = qd.y; Q[14] = qd.z; Q[15] = qd.w;                \
  }

#define PROC_B(W, Q)                                                       \
  {                                                                        \
    *ep = e1; ep += 64;                                                    \
    int t1e = dpp_shl1_i(e1);                                              \
    float f1n = pow2c(t1e - e1);                                           \
    _Pragma("unroll") for (int u = 0; u < 8; ++u) {                        \
      float pm1 = dpp_shl1(P1[0]) * f1n;                                   \
      float pm2 = dpp_shl1(P2[0]) * f1n;                                   \
      float cu[4];                                                         \
      _Pragma("unroll") for (int k = 0; k < 4; ++k) {                      \
        float a1 = (k == 3) ? pm1 : P1[k + 1];                             \
        float a2 = (k == 3) ? pm2 : P2[k + 1];                             \
        cu[k] = fmaf(wdl[k], a1,                                           \
                     fmaf(W[k][12 - u - k], a2, Q[13 - u - k] * P1[k]));   \
      }                                                                    \
      *(f4u*)sp = f4u{cu[3], cu[2], cu[1], cu[0]};                         \
      sp -= ROWS + 1;                                                      \
      _Pragma("unroll") for (int k = 0; k < 4; ++k) {                      \
        P2[k] = P1[k]; P1[k] = cu[k];                                      \
      }                                                                    \
    }                                                                      \
    float m = fmaxf(fmaxf(P1[0], P1[1]), fmaxf(P1[2], P1[3]));             \
    int ex = (m > 0.f) ? ((__float_as_int(m) >> 23) - 126) : (t1e - e1);   \
    float sc = pow2c(-ex);                                                 \
    _Pragma("unroll") for (int k = 0; k < 4; ++k) {                        \
      P1[k] *= sc; P2[k] *= sc;                                            \
    }                                                                      \
    e1 += ex;                                                              \
  }

    LOAD_B(e0, W0, Q0);
    for (int it = 0; it < 31; ++it) {
      LOAD_B(e0 - 8, W1, Q1);
      PROC_B(W0, Q0);
      LOAD_B(e0 - 16, W0, Q0);
      PROC_B(W1, Q1);
      e0 -= 16;
    }
    LOAD_B(e0 - 8, W1, Q1);
    PROC_B(W0, Q0);  // s 13..6
    PROC_B(W1, Q1);  // s 5..-2 (rows -1/-2 land in row pad)
  }

  // publish: drain stores + write back this XCD's L2, then release the flag
  __threadfence();
  if (lane == 0)
    __hip_atomic_store(&flags[blockIdx.x], MAGIC, __ATOMIC_RELEASE,
                       __HIP_MEMORY_SCOPE_AGENT);
}

__global__ void k_out(const float* __restrict__ wts,
                      const float* __restrict__ aD,
                      const int* __restrict__ aEb,
                      const float* __restrict__ S,
                      float* __restrict__ out) {
  int c = blockIdx.x * blockDim.x + threadIdx.x;
  if (c >= NCLS) return;
  float M = __logf(aD[510 * ROWS + 256 + 255]) +
            (float)aEb[63 * 64 + 63] * LN2F + 16.0f;
  float s = S[c];
  out[c] = (c != 0 && s > 0.f) ? (wts[c] + M + __logf(s)) : NEG_SENTINEL;
}

extern "C" void kernel_launch(void* const* d_in, const int* in_sizes, int n_in,
                              void* d_out, int out_size, void* d_ws, size_t ws_size,
                              hipStream_t stream) {
  const int* ar = (const int*)d_in[0];
  const int* en = (const int*)d_in[1];
  const float* wts = (const float*)d_in[2];
  float* aD = (float*)d_ws;                  // 514 diag-rows x 768
  float* bDraw = aD + 514 * ROWS;            // 514 diag-rows x 768
  float* bD = bDraw + 2 * ROWS;              // beta rows -2..510
  int* aEb = (int*)(bDraw + 514 * ROWS);     // 64 blocks x 64 lanes
  int* bEb = aEb + 4096;
  float* S = (float*)(bEb + 4096);           // 676 class sums (atomic)
  unsigned* flags = (unsigned*)(S + NCLS);   // 2 device-scope DP-done flags
  k_fused<<<130, 256, 0, stream>>>(ar, en, wts, aD, bD, aEb, bEb, S, flags);
  k_out<<<3, 256, 0, stream>>>(wts, aD, aEb, S, (float*)d_out);
}